// Round 9
// baseline (449.390 us; speedup 1.0000x reference)
//
#include <hip/hip_runtime.h>

#define B_ 32
#define T_ 1024
#define C_ 384
#define MAXLEN_ 2048
#define NBINS_ 255
#define WPK1 442368          /* 36*24*512 packed bf16 elems per weight */
#define ARS 392              /* A-tile row stride in bf16 (16B-aligned) */
#define TROWS 64             /* output rows per tile */
#define NTILE 16             /* 1024/64 */

typedef __attribute__((ext_vector_type(8))) short short8v;   // 8 bf16 = 4 VGPRs
typedef __attribute__((ext_vector_type(4))) float floatx4;

__device__ __forceinline__ unsigned short f2bf(float f) {
    unsigned u = __float_as_uint(f);
    u += 0x7fffu + ((u >> 16) & 1u);   // RNE
    return (unsigned short)(u >> 16);
}

// hoist a wave-uniform pointer into SGPRs (saddr+voffset addressing, saves VGPRs)
__device__ __forceinline__ const unsigned short* rfl(const unsigned short* p) {
    unsigned long long u = (unsigned long long)p;
    unsigned lo = __builtin_amdgcn_readfirstlane((unsigned)u);
    unsigned hi = __builtin_amdgcn_readfirstlane((unsigned)(u >> 32));
    return (const unsigned short*)(((unsigned long long)hi << 32) | lo);
}

struct CvP {
    const float* xf;              // fp32 x input
    const unsigned short* wpk;    // packed weights; layer1 = +p*WPK1, layer2 = +(3+p)*WPK1
    const float* b1[3];  const float* g1[3];  const float* be1[3];
    const float* b2[3];  const float* g2[3];  const float* be2[3];
    const float* wo[3];  const float* bo[3];
    float* pred[3];
    const float* pbins; const float* pemb; const float* ptgt;  // p==2 fusion
};

// ---------------------------------------------------------------------------
// R17 = R16 (226us, VGPR 56+48, 2 blocks/CU, no spill) + two cuts:
//  (a) TROWS 62->64: K1 = 5 m-tiles (h1 rows t0-1..t0+64 valid, j<66) with a
//      SINGLE acc[15] (K2 reuses acc[0..11]) -> 60 AGPR + ~60 arch ~= 120
//      <= 128, still 4 waves/SIMD. Grid 1632 -> 1536 = exactly 3.0 rounds
//      at 2 blocks/CU: -5.9% blocks (= -6% stage/epilogue instances, the
//      dominant serial cost) at +5.9% MFMA (pipe only ~10% SIMD-busy).
//      m-tile 4 A-reads go past the 68 staged rows into the aliased scratch
//      (R13-proven): garbage feeds only C rows >= 66, which are discarded;
//      C rows 64,65 read only staged x rows 64..67. LDS = As[82 rows]
//      = 64,288 B with scratch aliased into rows 68..81.
//  (b) lgkm-only raw barrier before K2: __syncthreads drains vmcnt(0),
//      serializing the 6 layer2 B-prefetch loads; s_waitcnt lgkmcnt(0) +
//      s_barrier keeps them in flight (compiler still emits the vmcnt wait
//      at first bA use). sched_barrier(0) after per methodology rule #18.
// Spill canary: WRITE_SIZE > 5 MB next round => the +16 regs spilled,
// revert to TROWS=62.
// ---------------------------------------------------------------------------
__global__ __launch_bounds__(512, 4) void conv_fused3(CvP P)
{
    __shared__ unsigned short As[82 * ARS];      // 64,288 B total static LDS
    // scratch aliased into As rows 68..81 (byte offset 53,312; 7,968 B used
    // of 10,976 B slack). Read only as discarded tail-m-tile garbage in K1.
    float* redS  = (float*)&As[68 * ARS];        // [8][80]
    float* redQ  = redS + 640;                   // [8][80]
    float* prbuf = redQ + 640;                   // [512]
    float* mrsM  = prbuf + 512;                  // [66]
    float* mrsR  = mrsM + 66;                    // [66]
    int*   embi  = (int*)(mrsR + 66);            // [68]

    const int tid  = threadIdx.x;
    const int wave = tid >> 6;      // col group 0..7
    const int lane = tid & 63;
    const int lq   = lane >> 4;
    const int ln   = lane & 15;
    const int blk  = blockIdx.x;
    const int p    = blk >> 9;                      // predictor 0..2
    const int rem  = blk & 511;
    const int b    = rem >> 4;
    const int k    = rem & 15;
    const int t0   = k << 6;                        // output rows [t0, t0+63]
    const int nb   = wave * 48;                     // 48 cols per wave

    // ---- layer1 B prefetch, steps 0 and 1 (SGPR base + voffset) ----
    const unsigned short* b1s = rfl(P.wpk + (size_t)p * WPK1 + wave * 1536);
    const int lo8 = lane * 8;
    short8v bA[3], bB[3];
#pragma unroll
    for (int nt = 0; nt < 3; ++nt) {
        bA[nt] = *(const short8v*)(b1s + lo8 + (nt << 9));
        bB[nt] = *(const short8v*)(b1s + lo8 + 12288 + (nt << 9));
    }

    // ---- stage x rows t0-2 .. t0+65 into As rows 0..67 (zero halo) ----
    const bool fuse_emb = (p == 2);
    if (fuse_emb) {
        if (tid < 68) {
            const int t = t0 - 2 + tid;
            int lo = 0;
            if ((unsigned)t < (unsigned)T_) {
                const float tg = P.ptgt[(b << 10) + t];
                int hi = NBINS_;
                while (lo < hi) {
                    const int mid = (lo + hi) >> 1;
                    if (P.pbins[mid] < tg) lo = mid + 1; else hi = mid;
                }
            }
            embi[tid] = lo;
        }
        __syncthreads();
    }
    {
        int row = tid / 96;
        int c4  = tid - row * 96;
        while (row < 68) {
            const int t = t0 - 2 + row;
            uint2 pv = make_uint2(0u, 0u);
            if ((unsigned)t < (unsigned)T_) {
                float4 f = *(const float4*)(P.xf + ((size_t)(b << 10) + t) * C_ + c4 * 4);
                if (fuse_emb) {
                    const float* er = P.pemb + (size_t)embi[row] * C_ + c4 * 4;
                    f.x += er[0]; f.y += er[1]; f.z += er[2]; f.w += er[3];
                }
                asm("v_cvt_pk_bf16_f32 %0, %1, %2" : "=v"(pv.x) : "v"(f.x), "v"(f.y));
                asm("v_cvt_pk_bf16_f32 %0, %1, %2" : "=v"(pv.y) : "v"(f.z), "v"(f.w));
            }
            *(uint2*)&As[row * ARS + c4 * 4] = pv;
            c4 += 32; row += 5;
            if (c4 >= 96) { c4 -= 96; row += 1; }   // +512 linear
        }
    }
    __syncthreads();

    // single accumulator array: K1 uses [0..14] (60 AGPR), K2 reuses [0..11]
    floatx4 acc[15];
#pragma unroll
    for (int i = 0; i < 15; ++i) acc[i] = (floatx4){0.f, 0.f, 0.f, 0.f};

    const unsigned short* abase = &As[ln * ARS + lq * 8];

    // ========= K-loop 1: 5 m-tiles -> h1 rows j=0..79 (valid j<66) ========
    {
        int offA = lo8 + 2 * 12288;
        int offB = lo8 + 3 * 12288;
#pragma unroll
        for (int kc = 0; kc < 3; ++kc) {
#pragma unroll
            for (int h2 = 0; h2 < 6; ++h2) {
                const int hb = h2 * 64;
                const int r  = kc * 12 + h2 * 2;
                {   // even: consume bA
                    short8v afrag[5];
#pragma unroll
                    for (int mt = 0; mt < 5; ++mt)
                        afrag[mt] = *(const short8v*)(abase + (mt * 16 + kc) * ARS + hb);
                    __builtin_amdgcn_s_setprio(1);
#pragma unroll
                    for (int mt = 0; mt < 5; ++mt)
#pragma unroll
                        for (int nt = 0; nt < 3; ++nt)
                            acc[mt * 3 + nt] = __builtin_amdgcn_mfma_f32_16x16x32_bf16(
                                afrag[mt], bA[nt], acc[mt * 3 + nt], 0, 0, 0);
                    __builtin_amdgcn_s_setprio(0);
                    if (r + 2 < 36) {
#pragma unroll
                        for (int nt = 0; nt < 3; ++nt)
                            bA[nt] = *(const short8v*)(b1s + offA + (nt << 9));
                        offA += 24576;
                    }
                }
                {   // odd: consume bB
                    short8v afrag[5];
#pragma unroll
                    for (int mt = 0; mt < 5; ++mt)
                        afrag[mt] = *(const short8v*)(abase + (mt * 16 + kc) * ARS + hb + 32);
                    __builtin_amdgcn_s_setprio(1);
#pragma unroll
                    for (int mt = 0; mt < 5; ++mt)
#pragma unroll
                        for (int nt = 0; nt < 3; ++nt)
                            acc[mt * 3 + nt] = __builtin_amdgcn_mfma_f32_16x16x32_bf16(
                                afrag[mt], bB[nt], acc[mt * 3 + nt], 0, 0, 0);
                    __builtin_amdgcn_s_setprio(0);
                    if (r + 3 < 36) {
#pragma unroll
                        for (int nt = 0; nt < 3; ++nt)
                            bB[nt] = *(const short8v*)(b1s + offB + (nt << 9));
                        offB += 24576;
                    }
                }
            }
        }
    }
    __syncthreads();   // all As (incl. aliased-scratch garbage) reads done

    // ---- layer1 LN partials: bias+relu, per-wave shfl reduce ----
    // rows >= 66 carry garbage (possibly NaN) but are row-contained:
    // shfl reduce is within-row; mrs reads only rows < 66.
    {
        float c1b[3];
#pragma unroll
        for (int nt = 0; nt < 3; ++nt)
            c1b[nt] = P.b1[p][nb + nt * 16 + ln];
#pragma unroll
        for (int mt = 0; mt < 5; ++mt) {
#pragma unroll
            for (int rg = 0; rg < 4; ++rg) {
                float s = 0.f, q = 0.f;
#pragma unroll
                for (int nt = 0; nt < 3; ++nt) {
                    float v = acc[mt * 3 + nt][rg] + c1b[nt];
                    v = v > 0.f ? v : 0.f;
                    acc[mt * 3 + nt][rg] = v;
                    s += v; q += v * v;
                }
#pragma unroll
                for (int off = 1; off < 16; off <<= 1) {
                    s += __shfl_xor(s, off, 64);
                    q += __shfl_xor(q, off, 64);
                }
                if (ln == ((mt * 4 + rg) & 15)) {
                    redS[wave * 80 + mt * 16 + lq * 4 + rg] = s;
                    redQ[wave * 80 + mt * 16 + lq * 4 + rg] = q;
                }
            }
        }
    }
    __syncthreads();

    // ---- cross-wave reduce ONCE per valid row (66 threads) ----
    if (tid < 66) {
        float s = 0.f, q = 0.f;
#pragma unroll
        for (int w = 0; w < 8; ++w) {
            s += redS[w * 80 + tid];
            q += redQ[w * 80 + tid];
        }
        const float m = s * (1.f / 384.f);
        mrsM[tid] = m;
        mrsR[tid] = rsqrtf(q * (1.f / 384.f) - m * m + 1e-5f);
    }
    __syncthreads();

    // ---- LN1 finalize + write h1 bf16 in place into As rows 0..65 ----
    {
        float c1g[3], c1be[3];
#pragma unroll
        for (int nt = 0; nt < 3; ++nt) {
            c1g[nt]  = P.g1[p][nb + nt * 16 + ln];
            c1be[nt] = P.be1[p][nb + nt * 16 + ln];
        }
#pragma unroll
        for (int mt = 0; mt < 5; ++mt) {
#pragma unroll
            for (int rg = 0; rg < 4; ++rg) {
                const int j = mt * 16 + lq * 4 + rg;        // h1 row t0-1+j
                if (j < 66) {
                    const int th = t0 - 1 + j;
                    const float m  = mrsM[j];
                    const float rs = mrsR[j];
                    const bool valid = (unsigned)th < (unsigned)T_;
#pragma unroll
                    for (int nt = 0; nt < 3; ++nt) {
                        float v = (acc[mt * 3 + nt][rg] - m) * rs * c1g[nt] + c1be[nt];
                        if (!valid) v = 0.f;        // zero-pad halo (SAME conv)
                        As[j * ARS + nb + nt * 16 + ln] = f2bf(v);
                    }
                }
            }
        }
    }

    // ---- layer2 B prefetch (layer1 acc values now dead) ----
    const unsigned short* b2s = rfl(P.wpk + (size_t)(3 + p) * WPK1 + wave * 1536);
#pragma unroll
    for (int nt = 0; nt < 3; ++nt) {
        bA[nt] = *(const short8v*)(b2s + lo8 + (nt << 9));
        bB[nt] = *(const short8v*)(b2s + lo8 + 12288 + (nt << 9));
    }
    // lgkm-only barrier: orders the h1 ds_writes vs K2 ds_reads without
    // draining the 6 in-flight B-prefetch vmem loads (compiler emits the
    // vmcnt wait at first bA/bB use).
    asm volatile("s_waitcnt lgkmcnt(0)\n\ts_barrier" ::: "memory");
    __builtin_amdgcn_sched_barrier(0);

    // re-zero acc[0..11] for layer2
#pragma unroll
    for (int i = 0; i < 12; ++i) acc[i] = (floatx4){0.f, 0.f, 0.f, 0.f};

    // ========= K-loop 2: 4 m-tiles -> output rows i=0..63 (all valid) =====
    // i reads h1 local rows i..i+2 <= 65: all valid h1.
    {
        int offA = lo8 + 2 * 12288;
        int offB = lo8 + 3 * 12288;
#pragma unroll
        for (int kc = 0; kc < 3; ++kc) {
#pragma unroll
            for (int h2 = 0; h2 < 6; ++h2) {
                const int hb = h2 * 64;
                const int r  = kc * 12 + h2 * 2;
                {   // even: consume bA
                    short8v afrag[4];
#pragma unroll
                    for (int mt = 0; mt < 4; ++mt)
                        afrag[mt] = *(const short8v*)(abase + (mt * 16 + kc) * ARS + hb);
                    __builtin_amdgcn_s_setprio(1);
#pragma unroll
                    for (int mt = 0; mt < 4; ++mt)
#pragma unroll
                        for (int nt = 0; nt < 3; ++nt)
                            acc[mt * 3 + nt] = __builtin_amdgcn_mfma_f32_16x16x32_bf16(
                                afrag[mt], bA[nt], acc[mt * 3 + nt], 0, 0, 0);
                    __builtin_amdgcn_s_setprio(0);
                    if (r + 2 < 36) {
#pragma unroll
                        for (int nt = 0; nt < 3; ++nt)
                            bA[nt] = *(const short8v*)(b2s + offA + (nt << 9));
                        offA += 24576;
                    }
                }
                {   // odd: consume bB
                    short8v afrag[4];
#pragma unroll
                    for (int mt = 0; mt < 4; ++mt)
                        afrag[mt] = *(const short8v*)(abase + (mt * 16 + kc) * ARS + hb + 32);
                    __builtin_amdgcn_s_setprio(1);
#pragma unroll
                    for (int mt = 0; mt < 4; ++mt)
#pragma unroll
                        for (int nt = 0; nt < 3; ++nt)
                            acc[mt * 3 + nt] = __builtin_amdgcn_mfma_f32_16x16x32_bf16(
                                afrag[mt], bB[nt], acc[mt * 3 + nt], 0, 0, 0);
                    __builtin_amdgcn_s_setprio(0);
                    if (r + 3 < 36) {
#pragma unroll
                        for (int nt = 0; nt < 3; ++nt)
                            bB[nt] = *(const short8v*)(b2s + offB + (nt << 9));
                        offB += 24576;
                    }
                }
            }
        }
    }
    // redS/redQ/mrs rewrites below ordered after all epilogue-1 reads by
    // the pre-K2 barrier; As not written again.

    // ---- layer2 LN partials ----
    {
        float c2b[3];
#pragma unroll
        for (int nt = 0; nt < 3; ++nt)
            c2b[nt] = P.b2[p][nb + nt * 16 + ln];
#pragma unroll
        for (int mt = 0; mt < 4; ++mt) {
#pragma unroll
            for (int rg = 0; rg < 4; ++rg) {
                float s = 0.f, q = 0.f;
#pragma unroll
                for (int nt = 0; nt < 3; ++nt) {
                    float v = acc[mt * 3 + nt][rg] + c2b[nt];
                    v = v > 0.f ? v : 0.f;
                    acc[mt * 3 + nt][rg] = v;
                    s += v; q += v * v;
                }
#pragma unroll
                for (int off = 1; off < 16; off <<= 1) {
                    s += __shfl_xor(s, off, 64);
                    q += __shfl_xor(q, off, 64);
                }
                if (ln == ((mt * 4 + rg) & 15)) {
                    redS[wave * 80 + mt * 16 + lq * 4 + rg] = s;
                    redQ[wave * 80 + mt * 16 + lq * 4 + rg] = q;
                }
            }
        }
    }
    __syncthreads();

    if (tid < 64) {
        float s = 0.f, q = 0.f;
#pragma unroll
        for (int w = 0; w < 8; ++w) {
            s += redS[w * 80 + tid];
            q += redQ[w * 80 + tid];
        }
        const float m = s * (1.f / 384.f);
        mrsM[tid] = m;
        mrsR[tid] = rsqrtf(q * (1.f / 384.f) - m * m + 1e-5f);
    }
    __syncthreads();

    // ---- LN2 finalize + projection dot ----
    {
        float c2g[3], c2be[3], cwo[3];
#pragma unroll
        for (int nt = 0; nt < 3; ++nt) {
            c2g[nt]  = P.g2[p][nb + nt * 16 + ln];
            c2be[nt] = P.be2[p][nb + nt * 16 + ln];
            cwo[nt]  = P.wo[p][nb + nt * 16 + ln];
        }
#pragma unroll
        for (int mt = 0; mt < 4; ++mt) {
#pragma unroll
            for (int rg = 0; rg < 4; ++rg) {
                const int row = mt * 16 + lq * 4 + rg;
                const float m  = mrsM[row];
                const float rs = mrsR[row];
                float pr = 0.f;
#pragma unroll
                for (int nt = 0; nt < 3; ++nt)
                    pr += ((acc[mt * 3 + nt][rg] - m) * rs * c2g[nt] + c2be[nt]) * cwo[nt];
#pragma unroll
                for (int off = 1; off < 16; off <<= 1)
                    pr += __shfl_xor(pr, off, 64);
                if (ln == ((mt * 4 + rg) & 15))
                    prbuf[wave * 64 + row] = pr;
            }
        }
    }
    __syncthreads();
    if (tid < 64) {
        float s = P.bo[p][0];
#pragma unroll
        for (int w = 0; w < 8; ++w) s += prbuf[w * 64 + tid];
        P.pred[p][(b << 10) + t0 + tid] = s;
    }
}

// ---------------------------------------------------------------------------
// Coalesced weight pack via LDS transpose. Grid: 216 blocks = 6 wsel x 36 r.
// wpk[(r*24 + c16)*512 + lane*8 + j] = w[(r*32 + lq*8 + j)*384 + c16*16+ln]
// (c16 = 16-col fragment index 0..23 — consumed as wave*3+nt by conv)
// ---------------------------------------------------------------------------
#define WSS 388   /* LDS row stride (floats), 16B-aligned */
__global__ __launch_bounds__(256) void pack_w_kernel(
    const float* __restrict__ s0, const float* __restrict__ s1,
    const float* __restrict__ s2, const float* __restrict__ s3,
    const float* __restrict__ s4, const float* __restrict__ s5,
    unsigned short* __restrict__ dst)
{
    __shared__ float ws[32 * WSS];   // 48.5 KB
    const int blk  = blockIdx.x;
    const int wsel = blk / 36;
    const int r    = blk - wsel * 36;
    const float* src = wsel == 0 ? s0 : wsel == 1 ? s1 : wsel == 2 ? s2
                     : wsel == 3 ? s3 : wsel == 4 ? s4 : s5;
    const int tid = threadIdx.x;

    // coalesced load: 32 rows x 384 cols = 3072 float4
    const float* sb = src + (size_t)r * 32 * C_;
    for (int i4 = tid; i4 < 3072; i4 += 256) {
        const int k  = i4 / 96;
        const int n4 = i4 - k * 96;
        *(float4*)&ws[k * WSS + n4 * 4] = *(const float4*)(sb + (size_t)k * C_ + n4 * 4);
    }
    __syncthreads();

    // transpose-write: 1536 chunks of 8 bf16 (16 B), coalesced
    unsigned short* db = dst + (size_t)wsel * WPK1 + (size_t)r * 12288;
    for (int c = tid; c < 1536; c += 256) {
        const int lane = c & 63;
        const int wnt  = c >> 6;          // c16 fragment index 0..23
        const int ln   = lane & 15;
        const int lq   = lane >> 4;
        const int n    = wnt * 16 + ln;
        ushort4 o0, o1;
        unsigned short e[8];
#pragma unroll
        for (int j = 0; j < 8; ++j)
            e[j] = f2bf(ws[(lq * 8 + j) * WSS + n]);
        o0 = make_ushort4(e[0], e[1], e[2], e[3]);
        o1 = make_ushort4(e[4], e[5], e[6], e[7]);
        *(ushort4*)(db + wnt * 512 + lane * 8)     = o0;
        *(ushort4*)(db + wnt * 512 + lane * 8 + 4) = o1;
    }
}

// Fused: per-batch cumsum of duration + per-frame packed gather index
// pk = t | plo<<10 | elo<<19 (or -1 if frame >= total); mel_len.
__global__ __launch_bounds__(256) void cumsum_idx_kernel(
    const int* __restrict__ dur,
    const float* __restrict__ pbins, const float* __restrict__ ptgt,
    const float* __restrict__ ebins, const float* __restrict__ etgt,
    int* __restrict__ xidx, float* __restrict__ mel_len)
{
    __shared__ int cs[T_];
    __shared__ int part[256];
    __shared__ float pb[NBINS_], eb[NBINS_];
    const int b = blockIdx.x;
    const int tid = threadIdx.x;
    if (tid < NBINS_) { pb[tid] = pbins[tid]; eb[tid] = ebins[tid]; }
    int l[4];
    int s = 0;
#pragma unroll
    for (int i = 0; i < 4; ++i) { l[i] = dur[(b << 10) + tid * 4 + i]; s += l[i]; }
    part[tid] = s;
    __syncthreads();
    for (int off = 1; off < 256; off <<= 1) {
        int u = 0;
        if (tid >= off) u = part[tid - off];
        __syncthreads();
        part[tid] += u;
        __syncthreads();
    }
    const int incl = part[tid];
    int run = incl - s;
#pragma unroll
    for (int i = 0; i < 4; ++i) {
        run += l[i];
        cs[tid * 4 + i] = run;
    }
    if (tid == 255) mel_len[b] = (float)incl;
    __syncthreads();
    const int total = cs[T_ - 1];
    for (int f = tid; f < MAXLEN_; f += 256) {
        int pk = -1;
        if (f < total) {
            int lo = 0, hi = T_;
            while (lo < hi) {
                const int mid = (lo + hi) >> 1;
                if (cs[mid] <= f) lo = mid + 1; else hi = mid;
            }
            const int t = lo > T_ - 1 ? T_ - 1 : lo;
            const int row = (b << 10) + t;
            const float ptg = ptgt[row];
            int plo = 0, phi = NBINS_;
            while (plo < phi) {
                const int mid = (plo + phi) >> 1;
                if (pb[mid] < ptg) plo = mid + 1; else phi = mid;
            }
            const float etg = etgt[row];
            int elo = 0, ehi = NBINS_;
            while (elo < ehi) {
                const int mid = (elo + ehi) >> 1;
                if (eb[mid] < etg) elo = mid + 1; else ehi = mid;
            }
            pk = t | (plo << 10) | (elo << 19);
        }
        xidx[(b << 11) + f] = pk;
    }
}

// out[b,frame,:] = pk<0 ? 0 : x[b,t,:] + pemb[plo] + eemb[elo]  (fp32 exact)
__global__ __launch_bounds__(256) void length_reg_kernel(
    const float* __restrict__ x, const int* __restrict__ xidx,
    const float* __restrict__ pemb, const float* __restrict__ eemb,
    float* __restrict__ out)
{
    const int g    = blockIdx.x * 256 + threadIdx.x;  // B*2048*96
    const int c4   = g % 96;
    const int rest = g / 96;
    const int frame = rest & (MAXLEN_ - 1);
    const int b     = rest >> 11;
    const int pk = xidx[(b << 11) + frame];
    float4 v = make_float4(0.f, 0.f, 0.f, 0.f);
    if (pk >= 0) {
        const int t   = pk & 1023;
        const int plo = (pk >> 10) & 511;
        const int elo = (pk >> 19) & 511;
        v = *(const float4*)(x + ((size_t)(b << 10) + t) * C_ + c4 * 4);
        const float4 pe = *(const float4*)(pemb + (size_t)plo * C_ + c4 * 4);
        const float4 ee = *(const float4*)(eemb + (size_t)elo * C_ + c4 * 4);
        v.x += pe.x + ee.x; v.y += pe.y + ee.y;
        v.z += pe.z + ee.z; v.w += pe.w + ee.w;
    }
    *(float4*)(out + (size_t)g * 4) = v;
}

extern "C" void kernel_launch(void* const* d_in, const int* in_sizes, int n_in,
                              void* d_out, int out_size, void* d_ws, size_t ws_size,
                              hipStream_t stream)
{
    const float* x        = (const float*)d_in[0];
    const int*   duration = (const int*)d_in[2];
    const float* P[3][10];
    for (int p = 0; p < 3; ++p)
        for (int q = 0; q < 10; ++q)
            P[p][q] = (const float*)d_in[4 + p * 10 + q];
    const float* pitch_bins    = (const float*)d_in[34];
    const float* energy_bins   = (const float*)d_in[35];
    const float* pitch_emb     = (const float*)d_in[36];
    const float* energy_emb    = (const float*)d_in[37];
    const float* pitch_target  = (const float*)d_in[38];
    const float* energy_target = (const float*)d_in[39];

    float* out_x      = (float*)d_out;                       // (B,2048,384)
    float* out_pitch  = out_x + (size_t)B_ * MAXLEN_ * C_;
    float* out_energy = out_pitch + B_ * T_;
    float* out_logdur = out_energy + B_ * T_;
    float* out_mellen = out_logdur + B_ * T_;

    unsigned short* wpk = (unsigned short*)d_ws;             // 6*WPK1 bf16
    int* xidx = (int*)(wpk + (size_t)6 * WPK1);              // B*2048 ints

    const dim3 blk(256);
    const dim3 cblk(512);

    pack_w_kernel<<<216, blk, 0, stream>>>(
        P[0][0], P[0][4], P[1][0], P[1][4], P[2][0], P[2][4], wpk);

    CvP Pa;
    Pa.xf = x; Pa.wpk = wpk;
    for (int p = 0; p < 3; ++p) {
        Pa.b1[p]  = P[p][1];
        Pa.g1[p]  = P[p][2];
        Pa.be1[p] = P[p][3];
        Pa.b2[p]  = P[p][5];
        Pa.g2[p]  = P[p][6];
        Pa.be2[p] = P[p][7];
        Pa.wo[p]  = P[p][8];
        Pa.bo[p]  = P[p][9];
    }
    Pa.pred[0] = out_logdur; Pa.pred[1] = out_pitch; Pa.pred[2] = out_energy;
    Pa.pbins = pitch_bins; Pa.pemb = pitch_emb; Pa.ptgt = pitch_target;

    conv_fused3<<<3 * B_ * NTILE, cblk, 0, stream>>>(Pa);

    cumsum_idx_kernel<<<B_, blk, 0, stream>>>(
        duration, pitch_bins, pitch_target, energy_bins, energy_target,
        xidx, out_mellen);
    length_reg_kernel<<<24576, blk, 0, stream>>>(
        x, xidx, pitch_emb, energy_emb, out_x);
}

// Round 10
// 439.063 us; speedup vs baseline: 1.0235x; 1.0235x over previous
//
#include <hip/hip_runtime.h>

#define B_ 32
#define T_ 1024
#define C_ 384
#define MAXLEN_ 2048
#define NBINS_ 255
#define WPK1 442368          /* 36*24*512 packed bf16 elems per weight */
#define ARS 392              /* A-tile row stride in bf16 (16B-aligned) */
#define TROWS 64             /* output rows per tile */
#define NTILE 16             /* 1024/64 */

typedef __attribute__((ext_vector_type(8))) short short8v;   // 8 bf16 = 4 VGPRs
typedef __attribute__((ext_vector_type(4))) float floatx4;

__device__ __forceinline__ unsigned short f2bf(float f) {
    unsigned u = __float_as_uint(f);
    u += 0x7fffu + ((u >> 16) & 1u);   // RNE
    return (unsigned short)(u >> 16);
}

// hoist a wave-uniform pointer into SGPRs (saddr+voffset addressing, saves VGPRs)
__device__ __forceinline__ const unsigned short* rfl(const unsigned short* p) {
    unsigned long long u = (unsigned long long)p;
    unsigned lo = __builtin_amdgcn_readfirstlane((unsigned)u);
    unsigned hi = __builtin_amdgcn_readfirstlane((unsigned)(u >> 32));
    return (const unsigned short*)(((unsigned long long)hi << 32) | lo);
}

struct CvP {
    const float* xf;              // fp32 x input
    const unsigned short* wpk;    // packed weights; layer1 = +p*WPK1, layer2 = +(3+p)*WPK1
    const float* b1[3];  const float* g1[3];  const float* be1[3];
    const float* b2[3];  const float* g2[3];  const float* be2[3];
    const float* wo[3];  const float* bo[3];
    float* pred[3];
    const float* pbins; const float* pemb; const float* ptgt;  // p==2 fusion
};

// ---------------------------------------------------------------------------
// R18 = R17 (223us) + L2-sharing grid schedule. R17 diagnosis: FETCH 104MB
// at 478 GB/s ~= the whole 223us dispatch — staging x is re-read once per
// predictor with p-major ordering (re-reads 500 blocks apart) and default
// round-robin XCD placement (adjacent blocks on different L2s) -> zero
// reuse. MFMA floor (972 MFMA/wave x 16 waves/CU x 4.85cy) = 42% of round,
// matching MfmaUtil 40.6 — the other 58% is stage latency + epilogues.
// Changes:
//  (a) p-FASTEST logical order L = tile*3+p, dispatched via bijective
//      XCD-chunked swizzle L = (D&7)*192 + (D>>3)  [1536 = 8*192]:
//      the 3 predictors of a tile become dispatch-adjacent ON THE SAME XCD
//      -> 2 of 3 x-stages hit that XCD's L2 (~200cy vs ~900cy HBM).
//      Per-XCD round working set ~21 tiles x 104KB = 2.2MB <= 4MB L2.
//  (b) stage loop: fixed 13-trip #pragma unroll (guarded) so several
//      x-loads stay in flight instead of one serial-dependent chain.
// Canaries: FETCH not dropping => XCD D%8 assumption wrong (revert a);
// WRITE > 5MB => unroll spilled (revert b).
// ---------------------------------------------------------------------------
__global__ __launch_bounds__(512, 4) void conv_fused3(CvP P)
{
    __shared__ unsigned short As[82 * ARS];      // 64,288 B total static LDS
    // scratch aliased into As rows 68..81 (byte offset 53,312; 7,968 B used
    // of 10,976 B slack). Read only as discarded tail-m-tile garbage in K1.
    float* redS  = (float*)&As[68 * ARS];        // [8][80]
    float* redQ  = redS + 640;                   // [8][80]
    float* prbuf = redQ + 640;                   // [512]
    float* mrsM  = prbuf + 512;                  // [66]
    float* mrsR  = mrsM + 66;                    // [66]
    int*   embi  = (int*)(mrsR + 66);            // [68]

    const int tid  = threadIdx.x;
    const int wave = tid >> 6;      // col group 0..7
    const int lane = tid & 63;
    const int lq   = lane >> 4;
    const int ln   = lane & 15;

    // bijective XCD-chunked mapping (8 XCDs, 1536 blocks, chunk 192):
    // dispatch D -> logical L; L = tile*3 + p (p fastest => triple adjacent
    // on one XCD => x staged by p=0 is L2-hot for p=1,2).
    const int D    = blockIdx.x;
    const int L    = ((D & 7) * 192) + (D >> 3);
    const int tile = L / 3;                         // 0..511
    const int p    = L - tile * 3;                  // predictor 0..2
    const int b    = tile >> 4;
    const int k    = tile & 15;
    const int t0   = k << 6;                        // output rows [t0, t0+63]
    const int nb   = wave * 48;                     // 48 cols per wave

    // ---- layer1 B prefetch, steps 0 and 1 (SGPR base + voffset) ----
    const unsigned short* b1s = rfl(P.wpk + (size_t)p * WPK1 + wave * 1536);
    const int lo8 = lane * 8;
    short8v bA[3], bB[3];
#pragma unroll
    for (int nt = 0; nt < 3; ++nt) {
        bA[nt] = *(const short8v*)(b1s + lo8 + (nt << 9));
        bB[nt] = *(const short8v*)(b1s + lo8 + 12288 + (nt << 9));
    }

    // ---- stage x rows t0-2 .. t0+65 into As rows 0..67 (zero halo) ----
    const bool fuse_emb = (p == 2);
    if (fuse_emb) {
        if (tid < 68) {
            const int t = t0 - 2 + tid;
            int lo = 0;
            if ((unsigned)t < (unsigned)T_) {
                const float tg = P.ptgt[(b << 10) + t];
                int hi = NBINS_;
                while (lo < hi) {
                    const int mid = (lo + hi) >> 1;
                    if (P.pbins[mid] < tg) lo = mid + 1; else hi = mid;
                }
            }
            embi[tid] = lo;
        }
        __syncthreads();
    }
#pragma unroll
    for (int it = 0; it < 13; ++it) {
        const int i = tid + it * 512;
        if (i < 68 * 96) {
            const int row = i / 96;
            const int c4  = i - row * 96;
            const int t   = t0 - 2 + row;
            uint2 pv = make_uint2(0u, 0u);
            if ((unsigned)t < (unsigned)T_) {
                float4 f = *(const float4*)(P.xf + ((size_t)(b << 10) + t) * C_ + c4 * 4);
                if (fuse_emb) {
                    const float* er = P.pemb + (size_t)embi[row] * C_ + c4 * 4;
                    f.x += er[0]; f.y += er[1]; f.z += er[2]; f.w += er[3];
                }
                asm("v_cvt_pk_bf16_f32 %0, %1, %2" : "=v"(pv.x) : "v"(f.x), "v"(f.y));
                asm("v_cvt_pk_bf16_f32 %0, %1, %2" : "=v"(pv.y) : "v"(f.z), "v"(f.w));
            }
            *(uint2*)&As[row * ARS + c4 * 4] = pv;
        }
    }
    __syncthreads();

    // single accumulator array: K1 uses [0..14] (60 AGPR), K2 reuses [0..11]
    floatx4 acc[15];
#pragma unroll
    for (int i = 0; i < 15; ++i) acc[i] = (floatx4){0.f, 0.f, 0.f, 0.f};

    const unsigned short* abase = &As[ln * ARS + lq * 8];

    // ========= K-loop 1: 5 m-tiles -> h1 rows j=0..79 (valid j<66) ========
    {
        int offA = lo8 + 2 * 12288;
        int offB = lo8 + 3 * 12288;
#pragma unroll
        for (int kc = 0; kc < 3; ++kc) {
#pragma unroll
            for (int h2 = 0; h2 < 6; ++h2) {
                const int hb = h2 * 64;
                const int r  = kc * 12 + h2 * 2;
                {   // even: consume bA
                    short8v afrag[5];
#pragma unroll
                    for (int mt = 0; mt < 5; ++mt)
                        afrag[mt] = *(const short8v*)(abase + (mt * 16 + kc) * ARS + hb);
                    __builtin_amdgcn_s_setprio(1);
#pragma unroll
                    for (int mt = 0; mt < 5; ++mt)
#pragma unroll
                        for (int nt = 0; nt < 3; ++nt)
                            acc[mt * 3 + nt] = __builtin_amdgcn_mfma_f32_16x16x32_bf16(
                                afrag[mt], bA[nt], acc[mt * 3 + nt], 0, 0, 0);
                    __builtin_amdgcn_s_setprio(0);
                    if (r + 2 < 36) {
#pragma unroll
                        for (int nt = 0; nt < 3; ++nt)
                            bA[nt] = *(const short8v*)(b1s + offA + (nt << 9));
                        offA += 24576;
                    }
                }
                {   // odd: consume bB
                    short8v afrag[5];
#pragma unroll
                    for (int mt = 0; mt < 5; ++mt)
                        afrag[mt] = *(const short8v*)(abase + (mt * 16 + kc) * ARS + hb + 32);
                    __builtin_amdgcn_s_setprio(1);
#pragma unroll
                    for (int mt = 0; mt < 5; ++mt)
#pragma unroll
                        for (int nt = 0; nt < 3; ++nt)
                            acc[mt * 3 + nt] = __builtin_amdgcn_mfma_f32_16x16x32_bf16(
                                afrag[mt], bB[nt], acc[mt * 3 + nt], 0, 0, 0);
                    __builtin_amdgcn_s_setprio(0);
                    if (r + 3 < 36) {
#pragma unroll
                        for (int nt = 0; nt < 3; ++nt)
                            bB[nt] = *(const short8v*)(b1s + offB + (nt << 9));
                        offB += 24576;
                    }
                }
            }
        }
    }
    __syncthreads();   // all As (incl. aliased-scratch garbage) reads done

    // ---- layer1 LN partials: bias+relu, per-wave shfl reduce ----
    // rows >= 66 carry garbage (possibly NaN) but are row-contained:
    // shfl reduce is within-row; mrs reads only rows < 66.
    {
        float c1b[3];
#pragma unroll
        for (int nt = 0; nt < 3; ++nt)
            c1b[nt] = P.b1[p][nb + nt * 16 + ln];
#pragma unroll
        for (int mt = 0; mt < 5; ++mt) {
#pragma unroll
            for (int rg = 0; rg < 4; ++rg) {
                float s = 0.f, q = 0.f;
#pragma unroll
                for (int nt = 0; nt < 3; ++nt) {
                    float v = acc[mt * 3 + nt][rg] + c1b[nt];
                    v = v > 0.f ? v : 0.f;
                    acc[mt * 3 + nt][rg] = v;
                    s += v; q += v * v;
                }
#pragma unroll
                for (int off = 1; off < 16; off <<= 1) {
                    s += __shfl_xor(s, off, 64);
                    q += __shfl_xor(q, off, 64);
                }
                if (ln == ((mt * 4 + rg) & 15)) {
                    redS[wave * 80 + mt * 16 + lq * 4 + rg] = s;
                    redQ[wave * 80 + mt * 16 + lq * 4 + rg] = q;
                }
            }
        }
    }
    __syncthreads();

    // ---- cross-wave reduce ONCE per valid row (66 threads) ----
    if (tid < 66) {
        float s = 0.f, q = 0.f;
#pragma unroll
        for (int w = 0; w < 8; ++w) {
            s += redS[w * 80 + tid];
            q += redQ[w * 80 + tid];
        }
        const float m = s * (1.f / 384.f);
        mrsM[tid] = m;
        mrsR[tid] = rsqrtf(q * (1.f / 384.f) - m * m + 1e-5f);
    }
    __syncthreads();

    // ---- LN1 finalize + write h1 bf16 in place into As rows 0..65 ----
    {
        float c1g[3], c1be[3];
#pragma unroll
        for (int nt = 0; nt < 3; ++nt) {
            c1g[nt]  = P.g1[p][nb + nt * 16 + ln];
            c1be[nt] = P.be1[p][nb + nt * 16 + ln];
        }
#pragma unroll
        for (int mt = 0; mt < 5; ++mt) {
#pragma unroll
            for (int rg = 0; rg < 4; ++rg) {
                const int j = mt * 16 + lq * 4 + rg;        // h1 row t0-1+j
                if (j < 66) {
                    const int th = t0 - 1 + j;
                    const float m  = mrsM[j];
                    const float rs = mrsR[j];
                    const bool valid = (unsigned)th < (unsigned)T_;
#pragma unroll
                    for (int nt = 0; nt < 3; ++nt) {
                        float v = (acc[mt * 3 + nt][rg] - m) * rs * c1g[nt] + c1be[nt];
                        if (!valid) v = 0.f;        // zero-pad halo (SAME conv)
                        As[j * ARS + nb + nt * 16 + ln] = f2bf(v);
                    }
                }
            }
        }
    }

    // ---- layer2 B prefetch (layer1 acc values now dead) ----
    const unsigned short* b2s = rfl(P.wpk + (size_t)(3 + p) * WPK1 + wave * 1536);
#pragma unroll
    for (int nt = 0; nt < 3; ++nt) {
        bA[nt] = *(const short8v*)(b2s + lo8 + (nt << 9));
        bB[nt] = *(const short8v*)(b2s + lo8 + 12288 + (nt << 9));
    }
    // lgkm-only barrier: orders the h1 ds_writes vs K2 ds_reads without
    // draining the 6 in-flight B-prefetch vmem loads (compiler emits the
    // vmcnt wait at first bA/bB use).
    asm volatile("s_waitcnt lgkmcnt(0)\n\ts_barrier" ::: "memory");
    __builtin_amdgcn_sched_barrier(0);

    // re-zero acc[0..11] for layer2
#pragma unroll
    for (int i = 0; i < 12; ++i) acc[i] = (floatx4){0.f, 0.f, 0.f, 0.f};

    // ========= K-loop 2: 4 m-tiles -> output rows i=0..63 (all valid) =====
    // i reads h1 local rows i..i+2 <= 65: all valid h1.
    {
        int offA = lo8 + 2 * 12288;
        int offB = lo8 + 3 * 12288;
#pragma unroll
        for (int kc = 0; kc < 3; ++kc) {
#pragma unroll
            for (int h2 = 0; h2 < 6; ++h2) {
                const int hb = h2 * 64;
                const int r  = kc * 12 + h2 * 2;
                {   // even: consume bA
                    short8v afrag[4];
#pragma unroll
                    for (int mt = 0; mt < 4; ++mt)
                        afrag[mt] = *(const short8v*)(abase + (mt * 16 + kc) * ARS + hb);
                    __builtin_amdgcn_s_setprio(1);
#pragma unroll
                    for (int mt = 0; mt < 4; ++mt)
#pragma unroll
                        for (int nt = 0; nt < 3; ++nt)
                            acc[mt * 3 + nt] = __builtin_amdgcn_mfma_f32_16x16x32_bf16(
                                afrag[mt], bA[nt], acc[mt * 3 + nt], 0, 0, 0);
                    __builtin_amdgcn_s_setprio(0);
                    if (r + 2 < 36) {
#pragma unroll
                        for (int nt = 0; nt < 3; ++nt)
                            bA[nt] = *(const short8v*)(b2s + offA + (nt << 9));
                        offA += 24576;
                    }
                }
                {   // odd: consume bB
                    short8v afrag[4];
#pragma unroll
                    for (int mt = 0; mt < 4; ++mt)
                        afrag[mt] = *(const short8v*)(abase + (mt * 16 + kc) * ARS + hb + 32);
                    __builtin_amdgcn_s_setprio(1);
#pragma unroll
                    for (int mt = 0; mt < 4; ++mt)
#pragma unroll
                        for (int nt = 0; nt < 3; ++nt)
                            acc[mt * 3 + nt] = __builtin_amdgcn_mfma_f32_16x16x32_bf16(
                                afrag[mt], bB[nt], acc[mt * 3 + nt], 0, 0, 0);
                    __builtin_amdgcn_s_setprio(0);
                    if (r + 3 < 36) {
#pragma unroll
                        for (int nt = 0; nt < 3; ++nt)
                            bB[nt] = *(const short8v*)(b2s + offB + (nt << 9));
                        offB += 24576;
                    }
                }
            }
        }
    }
    // redS/redQ/mrs rewrites below ordered after all epilogue-1 reads by
    // the pre-K2 barrier; As not written again.

    // ---- layer2 LN partials ----
    {
        float c2b[3];
#pragma unroll
        for (int nt = 0; nt < 3; ++nt)
            c2b[nt] = P.b2[p][nb + nt * 16 + ln];
#pragma unroll
        for (int mt = 0; mt < 4; ++mt) {
#pragma unroll
            for (int rg = 0; rg < 4; ++rg) {
                float s = 0.f, q = 0.f;
#pragma unroll
                for (int nt = 0; nt < 3; ++nt) {
                    float v = acc[mt * 3 + nt][rg] + c2b[nt];
                    v = v > 0.f ? v : 0.f;
                    acc[mt * 3 + nt][rg] = v;
                    s += v; q += v * v;
                }
#pragma unroll
                for (int off = 1; off < 16; off <<= 1) {
                    s += __shfl_xor(s, off, 64);
                    q += __shfl_xor(q, off, 64);
                }
                if (ln == ((mt * 4 + rg) & 15)) {
                    redS[wave * 80 + mt * 16 + lq * 4 + rg] = s;
                    redQ[wave * 80 + mt * 16 + lq * 4 + rg] = q;
                }
            }
        }
    }
    __syncthreads();

    if (tid < 64) {
        float s = 0.f, q = 0.f;
#pragma unroll
        for (int w = 0; w < 8; ++w) {
            s += redS[w * 80 + tid];
            q += redQ[w * 80 + tid];
        }
        const float m = s * (1.f / 384.f);
        mrsM[tid] = m;
        mrsR[tid] = rsqrtf(q * (1.f / 384.f) - m * m + 1e-5f);
    }
    __syncthreads();

    // ---- LN2 finalize + projection dot ----
    {
        float c2g[3], c2be[3], cwo[3];
#pragma unroll
        for (int nt = 0; nt < 3; ++nt) {
            c2g[nt]  = P.g2[p][nb + nt * 16 + ln];
            c2be[nt] = P.be2[p][nb + nt * 16 + ln];
            cwo[nt]  = P.wo[p][nb + nt * 16 + ln];
        }
#pragma unroll
        for (int mt = 0; mt < 4; ++mt) {
#pragma unroll
            for (int rg = 0; rg < 4; ++rg) {
                const int row = mt * 16 + lq * 4 + rg;
                const float m  = mrsM[row];
                const float rs = mrsR[row];
                float pr = 0.f;
#pragma unroll
                for (int nt = 0; nt < 3; ++nt)
                    pr += ((acc[mt * 3 + nt][rg] - m) * rs * c2g[nt] + c2be[nt]) * cwo[nt];
#pragma unroll
                for (int off = 1; off < 16; off <<= 1)
                    pr += __shfl_xor(pr, off, 64);
                if (ln == ((mt * 4 + rg) & 15))
                    prbuf[wave * 64 + row] = pr;
            }
        }
    }
    __syncthreads();
    if (tid < 64) {
        float s = P.bo[p][0];
#pragma unroll
        for (int w = 0; w < 8; ++w) s += prbuf[w * 64 + tid];
        P.pred[p][(b << 10) + t0 + tid] = s;
    }
}

// ---------------------------------------------------------------------------
// Coalesced weight pack via LDS transpose. Grid: 216 blocks = 6 wsel x 36 r.
// wpk[(r*24 + c16)*512 + lane*8 + j] = w[(r*32 + lq*8 + j)*384 + c16*16+ln]
// (c16 = 16-col fragment index 0..23 — consumed as wave*3+nt by conv)
// ---------------------------------------------------------------------------
#define WSS 388   /* LDS row stride (floats), 16B-aligned */
__global__ __launch_bounds__(256) void pack_w_kernel(
    const float* __restrict__ s0, const float* __restrict__ s1,
    const float* __restrict__ s2, const float* __restrict__ s3,
    const float* __restrict__ s4, const float* __restrict__ s5,
    unsigned short* __restrict__ dst)
{
    __shared__ float ws[32 * WSS];   // 48.5 KB
    const int blk  = blockIdx.x;
    const int wsel = blk / 36;
    const int r    = blk - wsel * 36;
    const float* src = wsel == 0 ? s0 : wsel == 1 ? s1 : wsel == 2 ? s2
                     : wsel == 3 ? s3 : wsel == 4 ? s4 : s5;
    const int tid = threadIdx.x;

    // coalesced load: 32 rows x 384 cols = 3072 float4
    const float* sb = src + (size_t)r * 32 * C_;
    for (int i4 = tid; i4 < 3072; i4 += 256) {
        const int k  = i4 / 96;
        const int n4 = i4 - k * 96;
        *(float4*)&ws[k * WSS + n4 * 4] = *(const float4*)(sb + (size_t)k * C_ + n4 * 4);
    }
    __syncthreads();

    // transpose-write: 1536 chunks of 8 bf16 (16 B), coalesced
    unsigned short* db = dst + (size_t)wsel * WPK1 + (size_t)r * 12288;
    for (int c = tid; c < 1536; c += 256) {
        const int lane = c & 63;
        const int wnt  = c >> 6;          // c16 fragment index 0..23
        const int ln   = lane & 15;
        const int lq   = lane >> 4;
        const int n    = wnt * 16 + ln;
        ushort4 o0, o1;
        unsigned short e[8];
#pragma unroll
        for (int j = 0; j < 8; ++j)
            e[j] = f2bf(ws[(lq * 8 + j) * WSS + n]);
        o0 = make_ushort4(e[0], e[1], e[2], e[3]);
        o1 = make_ushort4(e[4], e[5], e[6], e[7]);
        *(ushort4*)(db + wnt * 512 + lane * 8)     = o0;
        *(ushort4*)(db + wnt * 512 + lane * 8 + 4) = o1;
    }
}

// Fused: per-batch cumsum of duration + per-frame packed gather index
// pk = t | plo<<10 | elo<<19 (or -1 if frame >= total); mel_len.
__global__ __launch_bounds__(256) void cumsum_idx_kernel(
    const int* __restrict__ dur,
    const float* __restrict__ pbins, const float* __restrict__ ptgt,
    const float* __restrict__ ebins, const float* __restrict__ etgt,
    int* __restrict__ xidx, float* __restrict__ mel_len)
{
    __shared__ int cs[T_];
    __shared__ int part[256];
    __shared__ float pb[NBINS_], eb[NBINS_];
    const int b = blockIdx.x;
    const int tid = threadIdx.x;
    if (tid < NBINS_) { pb[tid] = pbins[tid]; eb[tid] = ebins[tid]; }
    int l[4];
    int s = 0;
#pragma unroll
    for (int i = 0; i < 4; ++i) { l[i] = dur[(b << 10) + tid * 4 + i]; s += l[i]; }
    part[tid] = s;
    __syncthreads();
    for (int off = 1; off < 256; off <<= 1) {
        int u = 0;
        if (tid >= off) u = part[tid - off];
        __syncthreads();
        part[tid] += u;
        __syncthreads();
    }
    const int incl = part[tid];
    int run = incl - s;
#pragma unroll
    for (int i = 0; i < 4; ++i) {
        run += l[i];
        cs[tid * 4 + i] = run;
    }
    if (tid == 255) mel_len[b] = (float)incl;
    __syncthreads();
    const int total = cs[T_ - 1];
    for (int f = tid; f < MAXLEN_; f += 256) {
        int pk = -1;
        if (f < total) {
            int lo = 0, hi = T_;
            while (lo < hi) {
                const int mid = (lo + hi) >> 1;
                if (cs[mid] <= f) lo = mid + 1; else hi = mid;
            }
            const int t = lo > T_ - 1 ? T_ - 1 : lo;
            const int row = (b << 10) + t;
            const float ptg = ptgt[row];
            int plo = 0, phi = NBINS_;
            while (plo < phi) {
                const int mid = (plo + phi) >> 1;
                if (pb[mid] < ptg) plo = mid + 1; else phi = mid;
            }
            const float etg = etgt[row];
            int elo = 0, ehi = NBINS_;
            while (elo < ehi) {
                const int mid = (elo + ehi) >> 1;
                if (eb[mid] < etg) elo = mid + 1; else ehi = mid;
            }
            pk = t | (plo << 10) | (elo << 19);
        }
        xidx[(b << 11) + f] = pk;
    }
}

// out[b,frame,:] = pk<0 ? 0 : x[b,t,:] + pemb[plo] + eemb[elo]  (fp32 exact)
__global__ __launch_bounds__(256) void length_reg_kernel(
    const float* __restrict__ x, const int* __restrict__ xidx,
    const float* __restrict__ pemb, const float* __restrict__ eemb,
    float* __restrict__ out)
{
    const int g    = blockIdx.x * 256 + threadIdx.x;  // B*2048*96
    const int c4   = g % 96;
    const int rest = g / 96;
    const int frame = rest & (MAXLEN_ - 1);
    const int b     = rest >> 11;
    const int pk = xidx[(b << 11) + frame];
    float4 v = make_float4(0.f, 0.f, 0.f, 0.f);
    if (pk >= 0) {
        const int t   = pk & 1023;
        const int plo = (pk >> 10) & 511;
        const int elo = (pk >> 19) & 511;
        v = *(const float4*)(x + ((size_t)(b << 10) + t) * C_ + c4 * 4);
        const float4 pe = *(const float4*)(pemb + (size_t)plo * C_ + c4 * 4);
        const float4 ee = *(const float4*)(eemb + (size_t)elo * C_ + c4 * 4);
        v.x += pe.x + ee.x; v.y += pe.y + ee.y;
        v.z += pe.z + ee.z; v.w += pe.w + ee.w;
    }
    *(float4*)(out + (size_t)g * 4) = v;
}

extern "C" void kernel_launch(void* const* d_in, const int* in_sizes, int n_in,
                              void* d_out, int out_size, void* d_ws, size_t ws_size,
                              hipStream_t stream)
{
    const float* x        = (const float*)d_in[0];
    const int*   duration = (const int*)d_in[2];
    const float* P[3][10];
    for (int p = 0; p < 3; ++p)
        for (int q = 0; q < 10; ++q)
            P[p][q] = (const float*)d_in[4 + p * 10 + q];
    const float* pitch_bins    = (const float*)d_in[34];
    const float* energy_bins   = (const float*)d_in[35];
    const float* pitch_emb     = (const float*)d_in[36];
    const float* energy_emb    = (const float*)d_in[37];
    const float* pitch_target  = (const float*)d_in[38];
    const float* energy_target = (const float*)d_in[39];

    float* out_x      = (float*)d_out;                       // (B,2048,384)
    float* out_pitch  = out_x + (size_t)B_ * MAXLEN_ * C_;
    float* out_energy = out_pitch + B_ * T_;
    float* out_logdur = out_energy + B_ * T_;
    float* out_mellen = out_logdur + B_ * T_;

    unsigned short* wpk = (unsigned short*)d_ws;             // 6*WPK1 bf16
    int* xidx = (int*)(wpk + (size_t)6 * WPK1);              // B*2048 ints

    const dim3 blk(256);
    const dim3 cblk(512);

    pack_w_kernel<<<216, blk, 0, stream>>>(
        P[0][0], P[0][4], P[1][0], P[1][4], P[2][0], P[2][4], wpk);

    CvP Pa;
    Pa.xf = x; Pa.wpk = wpk;
    for (int p = 0; p < 3; ++p) {
        Pa.b1[p]  = P[p][1];
        Pa.g1[p]  = P[p][2];
        Pa.be1[p] = P[p][3];
        Pa.b2[p]  = P[p][5];
        Pa.g2[p]  = P[p][6];
        Pa.be2[p] = P[p][7];
        Pa.wo[p]  = P[p][8];
        Pa.bo[p]  = P[p][9];
    }
    Pa.pred[0] = out_logdur; Pa.pred[1] = out_pitch; Pa.pred[2] = out_energy;
    Pa.pbins = pitch_bins; Pa.pemb = pitch_emb; Pa.ptgt = pitch_target;

    conv_fused3<<<3 * B_ * NTILE, cblk, 0, stream>>>(Pa);

    cumsum_idx_kernel<<<B_, blk, 0, stream>>>(
        duration, pitch_bins, pitch_target, energy_bins, energy_target,
        xidx, out_mellen);
    length_reg_kernel<<<24576, blk, 0, stream>>>(
        x, xidx, pitch_emb, energy_emb, out_x);
}